// Round 2
// baseline (482.280 us; speedup 1.0000x reference)
//
#include <hip/hip_runtime.h>
#include <hip/hip_bf16.h>

#define HEADS  16
#define DIMH   64
#define NBATCH 2
#define SEQ    2048
#define DMODEL 1024
#define MROWS  (NBATCH * SEQ)   // 4096
#define TSPLIT 2                // t-range split for attention occupancy

typedef __attribute__((ext_vector_type(8))) short bf16x8;
typedef __attribute__((ext_vector_type(4))) float f32x4;
typedef __attribute__((ext_vector_type(4))) float float4v;
typedef __attribute__((ext_vector_type(4))) short short4v;

// ---------------- f32 -> bf16 cast (4 elems/thread) ----------------
__global__ void cvt_kernel(const float* __restrict__ in,
                           __hip_bfloat16* __restrict__ out, int n4) {
    int i = blockIdx.x * blockDim.x + threadIdx.x;
    if (i >= n4) return;
    float4v v = reinterpret_cast<const float4v*>(in)[i];
    union { short4v s; __hip_bfloat16 h[4]; } u;
#pragma unroll
    for (int j = 0; j < 4; ++j) u.h[j] = __float2bfloat16(v[j]);
    reinterpret_cast<short4v*>(out)[i] = u.s;
}

// -------- combine: ao = bf16(p0 + p1), 4 elems/thread --------
__global__ void combine_kernel(const float* __restrict__ p0,
                               const float* __restrict__ p1,
                               __hip_bfloat16* __restrict__ out, int n4) {
    int i = blockIdx.x * blockDim.x + threadIdx.x;
    if (i >= n4) return;
    float4v a = reinterpret_cast<const float4v*>(p0)[i];
    float4v b = reinterpret_cast<const float4v*>(p1)[i];
    union { short4v s; __hip_bfloat16 h[4]; } u;
#pragma unroll
    for (int j = 0; j < 4; ++j) u.h[j] = __float2bfloat16(a[j] + b[j]);
    reinterpret_cast<short4v*>(out)[i] = u.s;
}

// ------------- W [D][D] f32 -> WT [o][i] bf16 (transpose+cast) -------------
__global__ void tr_kernel(const float* __restrict__ W,
                          __hip_bfloat16* __restrict__ WT) {
    __shared__ float tile[32][33];
    int i = blockIdx.y * 32 + threadIdx.y;   // row of W
    int o = blockIdx.x * 32 + threadIdx.x;   // col of W
    tile[threadIdx.y][threadIdx.x] = W[i * DMODEL + o];
    __syncthreads();
    int oo = blockIdx.x * 32 + threadIdx.y;  // row of WT
    int ii = blockIdx.y * 32 + threadIdx.x;  // col of WT
    WT[oo * DMODEL + ii] = __float2bfloat16(tile[threadIdx.x][threadIdx.y]);
}

// ---------------- fused Q/KV projection GEMM ----------------
// hsb [4096][1024] bf16, WqT/WkvT [out][in] bf16.
// Writes q (pre-scaled by 1/8) [B,H,S,Dh], k [B,H,S,Dh], vt [B,H,Dh,S].
__launch_bounds__(256)
__global__ void proj_kernel(const __hip_bfloat16* __restrict__ hsb,
                            const __hip_bfloat16* __restrict__ WqT,
                            const __hip_bfloat16* __restrict__ WkvT,
                            __hip_bfloat16* __restrict__ qb,
                            __hip_bfloat16* __restrict__ kb,
                            __hip_bfloat16* __restrict__ vtb) {
    const int lane = threadIdx.x & 63;
    const int wave = threadIdx.x >> 6;
    const int lr = lane & 15;
    const int lk = lane >> 4;
    const int mbase = blockIdx.y * 64 + wave * 16;
    const int nb = blockIdx.x * 64;            // 0..2047 (q half then kv half)
    const bool is_q = nb < DMODEL;
    const __hip_bfloat16* __restrict__ WT = is_q ? WqT : WkvT;
    const int nbase = is_q ? nb : nb - DMODEL;

    f32x4 acc[4] = {};
    for (int k0 = 0; k0 < DMODEL; k0 += 32) {
        bf16x8 a = *reinterpret_cast<const bf16x8*>(
            &hsb[(size_t)(mbase + lr) * DMODEL + k0 + lk * 8]);
#pragma unroll
        for (int nt = 0; nt < 4; ++nt) {
            bf16x8 b = *reinterpret_cast<const bf16x8*>(
                &WT[(size_t)(nbase + nt * 16 + lr) * DMODEL + k0 + lk * 8]);
            acc[nt] = __builtin_amdgcn_mfma_f32_16x16x32_bf16(a, b, acc[nt], 0, 0, 0);
        }
    }
    // C layout: col = lane&15, row = (lane>>4)*4 + r
    const float qscale = is_q ? 0.125f : 1.0f;   // fold attention scale into Q
#pragma unroll
    for (int nt = 0; nt < 4; ++nt) {
#pragma unroll
        for (int r = 0; r < 4; ++r) {
            int m = mbase + lk * 4 + r;          // 0..4095
            int b_ = m >> 11, s = m & (SEQ - 1);
            int n = nbase + nt * 16 + lr;        // 0..1023
            int h = n >> 6, dh = n & 63;
            __hip_bfloat16 hv = __float2bfloat16(acc[nt][r] * qscale);
            size_t idx = ((size_t)(b_ * HEADS + h) * SEQ + s) * DIMH + dh;
            if (is_q) {
                qb[idx] = hv;
            } else {
                kb[idx] = hv;
                vtb[((size_t)(b_ * HEADS + h) * DIMH + dh) * SEQ + s] = hv;
            }
        }
    }
}

// ---------------- fused ReLU attention (t-split) ----------------
// grid: (B*H*(S/64), TSPLIT); 4 waves/block; wave owns 16 q-rows, no barriers.
// Writes f32 partial O per t-split to po[ts].
__launch_bounds__(256)
__global__ void attn_kernel(const __hip_bfloat16* __restrict__ qb,
                            const __hip_bfloat16* __restrict__ kb,
                            const __hip_bfloat16* __restrict__ vtb,
                            float* __restrict__ po) {
    __shared__ __align__(16) unsigned char Plds[4][16 * 128]; // per-wave P tile [16q][64t] bf16, XOR-swizzled
    const int lane = threadIdx.x & 63;
    const int wave = threadIdx.x >> 6;
    const int lr = lane & 15;
    const int lk = lane >> 4;
    const int bh = blockIdx.x >> 5;            // 0..31  (= b*16 + h)
    const int qblk = blockIdx.x & 31;
    const int ts = blockIdx.y;                 // t-split index
    const int b_ = bh >> 4, h = bh & 15;
    const int qbase = qblk * 64 + wave * 16;   // s-offset of this wave's q tile

    const __hip_bfloat16* __restrict__ Q = qb + (size_t)bh * SEQ * DIMH;
    const __hip_bfloat16* __restrict__ K = kb + (size_t)bh * SEQ * DIMH;
    const __hip_bfloat16* __restrict__ VT = vtb + (size_t)bh * DIMH * SEQ;
    unsigned char* P = Plds[wave];

    // Q fragments for this wave's 16 rows (Dh=64 -> 2 k-steps), loaded once.
    // Q is pre-scaled by 1/sqrt(Dh) at projection time.
    bf16x8 qf[2];
#pragma unroll
    for (int ks = 0; ks < 2; ++ks)
        qf[ks] = *reinterpret_cast<const bf16x8*>(
            &Q[(size_t)(qbase + lr) * DIMH + ks * 32 + lk * 8]);

    f32x4 acco[4] = {};
    const int tbeg = ts * (SEQ / TSPLIT);
    const int tend = tbeg + (SEQ / TSPLIT);

    for (int t0 = tbeg; t0 < tend; t0 += 64) {
        // ---- S = Q K^T over a 16q x 64t tile ----
        f32x4 sacc[4] = {};
#pragma unroll
        for (int nt = 0; nt < 4; ++nt) {
#pragma unroll
            for (int ks = 0; ks < 2; ++ks) {
                bf16x8 kf = *reinterpret_cast<const bf16x8*>(
                    &K[(size_t)(t0 + nt * 16 + lr) * DIMH + ks * 32 + lk * 8]);
                sacc[nt] = __builtin_amdgcn_mfma_f32_16x16x32_bf16(qf[ks], kf, sacc[nt], 0, 0, 0);
            }
        }
        // ---- relu(S) -> bf16 -> LDS (A-fragment layout, swizzled) ----
#pragma unroll
        for (int nt = 0; nt < 4; ++nt) {
#pragma unroll
            for (int r = 0; r < 4; ++r) {
                float v = sacc[nt][r];
                v = v > 0.f ? v : 0.f;
                int row = lk * 4 + r;
                int bytecol = (nt * 16 + lr) * 2;
                *reinterpret_cast<__hip_bfloat16*>(
                    &P[row * 128 + (bytecol ^ ((row & 7) << 4))]) = __float2bfloat16(v);
            }
        }
        // ---- O += P @ V ----
#pragma unroll
        for (int ks = 0; ks < 2; ++ks) {
            int bytecol = ks * 64 + lk * 16;
            bf16x8 pa = *reinterpret_cast<const bf16x8*>(
                &P[lr * 128 + (bytecol ^ ((lr & 7) << 4))]);
#pragma unroll
            for (int nt = 0; nt < 4; ++nt) {
                bf16x8 vb = *reinterpret_cast<const bf16x8*>(
                    &VT[(size_t)(nt * 16 + lr) * SEQ + t0 + ks * 32 + lk * 8]);
                acco[nt] = __builtin_amdgcn_mfma_f32_16x16x32_bf16(pa, vb, acco[nt], 0, 0, 0);
            }
        }
    }
    // ---- epilogue: po[ts] [B*S][D] f32, col = h*64 + dh ----
    float* __restrict__ PO = po + (size_t)ts * MROWS * DMODEL;
#pragma unroll
    for (int nt = 0; nt < 4; ++nt) {
#pragma unroll
        for (int r = 0; r < 4; ++r) {
            int s = qbase + lk * 4 + r;
            int col = h * 64 + nt * 16 + lr;
            PO[(size_t)(b_ * SEQ + s) * DMODEL + col] = acco[nt][r];
        }
    }
}

// ---------------- output projection GEMM + bias (f32 out) ----------------
__launch_bounds__(256)
__global__ void outproj_kernel(const __hip_bfloat16* __restrict__ ao,
                               const __hip_bfloat16* __restrict__ WoT,
                               const float* __restrict__ bout,
                               float* __restrict__ out) {
    const int lane = threadIdx.x & 63;
    const int wave = threadIdx.x >> 6;
    const int lr = lane & 15;
    const int lk = lane >> 4;
    const int mbase = blockIdx.y * 64 + wave * 16;
    const int nbase = blockIdx.x * 64;

    f32x4 acc[4] = {};
    for (int k0 = 0; k0 < DMODEL; k0 += 32) {
        bf16x8 a = *reinterpret_cast<const bf16x8*>(
            &ao[(size_t)(mbase + lr) * DMODEL + k0 + lk * 8]);
#pragma unroll
        for (int nt = 0; nt < 4; ++nt) {
            bf16x8 b = *reinterpret_cast<const bf16x8*>(
                &WoT[(size_t)(nbase + nt * 16 + lr) * DMODEL + k0 + lk * 8]);
            acc[nt] = __builtin_amdgcn_mfma_f32_16x16x32_bf16(a, b, acc[nt], 0, 0, 0);
        }
    }
#pragma unroll
    for (int nt = 0; nt < 4; ++nt) {
        float bias = bout[nbase + nt * 16 + lr];
#pragma unroll
        for (int r = 0; r < 4; ++r) {
            int m = mbase + lk * 4 + r;
            out[(size_t)m * DMODEL + nbase + nt * 16 + lr] = acc[nt][r] + bias;
        }
    }
}

extern "C" void kernel_launch(void* const* d_in, const int* in_sizes, int n_in,
                              void* d_out, int out_size, void* d_ws, size_t ws_size,
                              hipStream_t stream) {
    const float* hs   = (const float*)d_in[0];
    const float* Wq   = (const float*)d_in[1];
    const float* Wkv  = (const float*)d_in[2];
    const float* Wout = (const float*)d_in[3];
    const float* bout = (const float*)d_in[4];
    float* out = (float*)d_out;

    char* ws = (char*)d_ws;
    size_t off = 0;
    auto alloc = [&](size_t bytes) { char* p = ws + off; off += bytes; return p; };
    __hip_bfloat16* hsb  = (__hip_bfloat16*)alloc((size_t)MROWS * DMODEL * 2); // 8MB (dead after proj)
    __hip_bfloat16* WqT  = (__hip_bfloat16*)alloc((size_t)DMODEL * DMODEL * 2);
    __hip_bfloat16* WkvT = (__hip_bfloat16*)alloc((size_t)DMODEL * DMODEL * 2);
    __hip_bfloat16* WoT  = (__hip_bfloat16*)alloc((size_t)DMODEL * DMODEL * 2);
    __hip_bfloat16* qb   = (__hip_bfloat16*)alloc((size_t)MROWS * DMODEL * 2);
    __hip_bfloat16* kb   = (__hip_bfloat16*)alloc((size_t)MROWS * DMODEL * 2);
    __hip_bfloat16* vtb  = (__hip_bfloat16*)alloc((size_t)MROWS * DMODEL * 2);
    float*          po   = (float*)alloc((size_t)TSPLIT * MROWS * DMODEL * 4); // 32MB
    __hip_bfloat16* ao   = hsb;  // alias: hs_bf16 is dead once attention runs

    // 1. casts / transposes
    cvt_kernel<<<(MROWS * DMODEL / 4 + 255) / 256, 256, 0, stream>>>(hs, hsb, MROWS * DMODEL / 4);
    dim3 trg(32, 32), trb(32, 32);
    tr_kernel<<<trg, trb, 0, stream>>>(Wq, WqT);
    tr_kernel<<<trg, trb, 0, stream>>>(Wkv, WkvT);
    tr_kernel<<<trg, trb, 0, stream>>>(Wout, WoT);

    // 2. fused Q/KV projection (Q pre-scaled by 1/8)
    proj_kernel<<<dim3(2 * DMODEL / 64, MROWS / 64), 256, 0, stream>>>(hsb, WqT, WkvT, qb, kb, vtb);

    // 3. fused relu attention, t-split partials
    attn_kernel<<<dim3(NBATCH * HEADS * (SEQ / 64), TSPLIT), 256, 0, stream>>>(qb, kb, vtb, po);

    // 4. combine partials -> bf16 ao
    combine_kernel<<<(MROWS * DMODEL / 4 + 255) / 256, 256, 0, stream>>>(
        po, po + (size_t)MROWS * DMODEL, ao, MROWS * DMODEL / 4);

    // 5. output projection
    outproj_kernel<<<dim3(DMODEL / 64, MROWS / 64), 256, 0, stream>>>(ao, WoT, bout, out);
}

// Round 3
// 300.336 us; speedup vs baseline: 1.6058x; 1.6058x over previous
//
#include <hip/hip_runtime.h>
#include <hip/hip_bf16.h>

#define HEADS  16
#define DIMH   64
#define NBATCH 2
#define SEQ    2048
#define DMODEL 1024
#define MROWS  (NBATCH * SEQ)   // 4096

typedef __attribute__((ext_vector_type(8)))  short bf16x8;
typedef __attribute__((ext_vector_type(4)))  float f32x4;
typedef __attribute__((ext_vector_type(16))) float f32x16;
typedef __attribute__((ext_vector_type(4)))  float float4v;
typedef __attribute__((ext_vector_type(4)))  short short4v;

__device__ inline void glds16(const void* g, void* l) {
    __builtin_amdgcn_global_load_lds(
        (const __attribute__((address_space(1))) unsigned int*)g,
        (__attribute__((address_space(3))) unsigned int*)l, 16, 0, 0);
}

// ---------------- f32 -> bf16 cast (4 elems/thread) ----------------
__global__ void cvt_kernel(const float* __restrict__ in,
                           __hip_bfloat16* __restrict__ out, int n4) {
    int i = blockIdx.x * blockDim.x + threadIdx.x;
    if (i >= n4) return;
    float4v v = reinterpret_cast<const float4v*>(in)[i];
    union { short4v s; __hip_bfloat16 h[4]; } u;
#pragma unroll
    for (int j = 0; j < 4; ++j) u.h[j] = __float2bfloat16(v[j]);
    reinterpret_cast<short4v*>(out)[i] = u.s;
}

// ------------- W [D][D] f32 -> WT [o][i] bf16 (transpose+cast) -------------
__global__ void tr_kernel(const float* __restrict__ W,
                          __hip_bfloat16* __restrict__ WT) {
    __shared__ float tile[32][33];
    int i = blockIdx.y * 32 + threadIdx.y;   // row of W
    int o = blockIdx.x * 32 + threadIdx.x;   // col of W
    tile[threadIdx.y][threadIdx.x] = W[i * DMODEL + o];
    __syncthreads();
    int oo = blockIdx.x * 32 + threadIdx.y;  // row of WT
    int ii = blockIdx.y * 32 + threadIdx.x;  // col of WT
    WT[oo * DMODEL + ii] = __float2bfloat16(tile[threadIdx.x][threadIdx.y]);
}

// ---------------- fused Q/KV projection GEMM ----------------
// hsb [4096][1024] bf16, WqT/WkvT [out][in] bf16.
// Writes q (pre-scaled by 1/8) [B,H,S,Dh], k [B,H,S,Dh], vt [B,H,Dh,S].
__launch_bounds__(256)
__global__ void proj_kernel(const __hip_bfloat16* __restrict__ hsb,
                            const __hip_bfloat16* __restrict__ WqT,
                            const __hip_bfloat16* __restrict__ WkvT,
                            __hip_bfloat16* __restrict__ qb,
                            __hip_bfloat16* __restrict__ kb,
                            __hip_bfloat16* __restrict__ vtb) {
    const int lane = threadIdx.x & 63;
    const int wave = threadIdx.x >> 6;
    const int lr = lane & 15;
    const int lk = lane >> 4;
    const int mbase = blockIdx.y * 64 + wave * 16;
    const int nb = blockIdx.x * 64;            // 0..2047 (q half then kv half)
    const bool is_q = nb < DMODEL;
    const __hip_bfloat16* __restrict__ WT = is_q ? WqT : WkvT;
    const int nbase = is_q ? nb : nb - DMODEL;

    const __hip_bfloat16* arow = &hsb[(size_t)(mbase + lr) * DMODEL + lk * 8];
    const __hip_bfloat16* brow = &WT[(size_t)(nbase + lr) * DMODEL + lk * 8];

    // software-pipelined loads: batch next k-step's 5 loads before mfmas
    bf16x8 a  = *reinterpret_cast<const bf16x8*>(arow);
    bf16x8 b0 = *reinterpret_cast<const bf16x8*>(brow);
    bf16x8 b1 = *reinterpret_cast<const bf16x8*>(brow + 16 * DMODEL);
    bf16x8 b2 = *reinterpret_cast<const bf16x8*>(brow + 32 * DMODEL);
    bf16x8 b3 = *reinterpret_cast<const bf16x8*>(brow + 48 * DMODEL);
    f32x4 acc[4] = {};
    for (int k0 = 0; k0 < DMODEL; k0 += 32) {
        const int kn = (k0 + 32) & (DMODEL - 1);   // wrapped (harmless) prefetch
        bf16x8 an  = *reinterpret_cast<const bf16x8*>(arow + kn);
        bf16x8 bn0 = *reinterpret_cast<const bf16x8*>(brow + kn);
        bf16x8 bn1 = *reinterpret_cast<const bf16x8*>(brow + 16 * DMODEL + kn);
        bf16x8 bn2 = *reinterpret_cast<const bf16x8*>(brow + 32 * DMODEL + kn);
        bf16x8 bn3 = *reinterpret_cast<const bf16x8*>(brow + 48 * DMODEL + kn);
        acc[0] = __builtin_amdgcn_mfma_f32_16x16x32_bf16(a, b0, acc[0], 0, 0, 0);
        acc[1] = __builtin_amdgcn_mfma_f32_16x16x32_bf16(a, b1, acc[1], 0, 0, 0);
        acc[2] = __builtin_amdgcn_mfma_f32_16x16x32_bf16(a, b2, acc[2], 0, 0, 0);
        acc[3] = __builtin_amdgcn_mfma_f32_16x16x32_bf16(a, b3, acc[3], 0, 0, 0);
        a = an; b0 = bn0; b1 = bn1; b2 = bn2; b3 = bn3;
    }
    // C layout: col = lane&15, row = (lane>>4)*4 + r
    const float qscale = is_q ? 0.125f : 1.0f;   // fold attention scale into Q
#pragma unroll
    for (int nt = 0; nt < 4; ++nt) {
#pragma unroll
        for (int r = 0; r < 4; ++r) {
            int m = mbase + lk * 4 + r;          // 0..4095
            int b_ = m >> 11, s = m & (SEQ - 1);
            int n = nbase + nt * 16 + lr;        // 0..1023
            int h = n >> 6, dh = n & 63;
            __hip_bfloat16 hv = __float2bfloat16(acc[nt][r] * qscale);
            size_t idx = ((size_t)(b_ * HEADS + h) * SEQ + s) * DIMH + dh;
            if (is_q) {
                qb[idx] = hv;
            } else {
                kb[idx] = hv;
                vtb[((size_t)(b_ * HEADS + h) * DIMH + dh) * SEQ + s] = hv;
            }
        }
    }
}

// ---------------- fused ReLU attention, 32x32 MFMA + LDS-staged K/V ----------------
// grid: 512 blocks (32 bh x 16 qblk), 4 waves; wave owns 32 q rows; block 128.
// K,V^T tiles (64 t) double-buffered in LDS, XOR-swizzled; P stays in registers
// via swapped QK^T (S^T) + scrambled-t V reads (t-sum order agnostic).
__launch_bounds__(256, 2)
__global__ void attn_kernel(const __hip_bfloat16* __restrict__ qb,
                            const __hip_bfloat16* __restrict__ kb,
                            const __hip_bfloat16* __restrict__ vtb,
                            __hip_bfloat16* __restrict__ ao) {
    __shared__ __align__(16) char Klds[2][8192];
    __shared__ __align__(16) char Vlds[2][8192];
    const int lane = threadIdx.x & 63;
    const int wave = threadIdx.x >> 6;
    const int l32  = lane & 31;
    const int hi   = lane >> 5;

    // XCD-aware swizzle: 512 blocks -> 64 contiguous per XCD (bijective, 512%8==0)
    int bid = blockIdx.x;
    bid = (bid & 7) * 64 + (bid >> 3);
    const int bh   = bid >> 4;            // 0..31  (= b*16 + h)
    const int qblk = bid & 15;            // 0..15
    const int b_ = bh >> 4, h = bh & 15;
    const int qbase = qblk * 128 + wave * 32;

    const __hip_bfloat16* __restrict__ Q = qb + (size_t)bh * SEQ * DIMH;
    const char* __restrict__ Kg = (const char*)(kb  + (size_t)bh * SEQ * DIMH);
    const char* __restrict__ Vg = (const char*)(vtb + (size_t)bh * DIMH * SEQ);

    // Q fragments (B-operand): n = q = l32, k-elem j -> d = ks*16 + hi*8 + j
    bf16x8 qf[4];
#pragma unroll
    for (int ks = 0; ks < 4; ++ks)
        qf[ks] = *reinterpret_cast<const bf16x8*>(
            &Q[(size_t)(qbase + l32) * DIMH + ks * 16 + hi * 8]);

    f32x16 acco[2] = {};

    // stage one 64-t tile of K [64][64] and VT [64][64] (8KB each), linear LDS
    // dest + inverse-swizzled global source (swz = (row&7)<<4 on byte column)
    auto stage = [&](int buf, int t0) {
#pragma unroll
        for (int pass = 0; pass < 2; ++pass) {
            const int b   = wave * 2048 + pass * 1024 + lane * 16;
            const int row = b >> 7;
            const int cb  = (b & 127) ^ ((row & 7) << 4);
            glds16(Kg + (size_t)(t0 + row) * 128 + cb,
                   &Klds[buf][wave * 2048 + pass * 1024]);
            glds16(Vg + (size_t)row * (SEQ * 2) + t0 * 2 + cb,
                   &Vlds[buf][wave * 2048 + pass * 1024]);
        }
    };

    stage(0, 0);
    asm volatile("s_waitcnt vmcnt(0)" ::: "memory");
    __syncthreads();

    const int swz = (l32 & 7) << 4;
    int cur = 0;
    for (int t0 = 0; t0 < SEQ; t0 += 64) {
        if (t0 + 64 < SEQ) stage(cur ^ 1, t0 + 64);
        const char* Kc = Klds[cur];
        const char* Vc = Vlds[cur];

        // ---- S^T = K Q^T : A = K-frag (m=t), B = Q-frag (n=q) ----
        f32x16 s0 = {}, s1 = {};
#pragma unroll
        for (int ks = 0; ks < 4; ++ks) {
            bf16x8 k0f = *reinterpret_cast<const bf16x8*>(
                Kc + l32 * 128        + ((ks * 32 + 16 * hi) ^ swz));
            bf16x8 k1f = *reinterpret_cast<const bf16x8*>(
                Kc + (32 + l32) * 128 + ((ks * 32 + 16 * hi) ^ swz));
            s0 = __builtin_amdgcn_mfma_f32_32x32x16_bf16(k0f, qf[ks], s0, 0, 0, 0);
            s1 = __builtin_amdgcn_mfma_f32_32x32x16_bf16(k1f, qf[ks], s1, 0, 0, 0);
        }
        // ---- relu in-register ----
#pragma unroll
        for (int r = 0; r < 16; ++r) {
            s0[r] = fmaxf(s0[r], 0.f);
            s1[r] = fmaxf(s1[r], 0.f);
        }
        // ---- O += P V : lane's own S^T regs as A-frag; V read with matching
        //      scrambled t-order  t(kt,hi,j) = kt*16 + (j&3) + 8*(j>>2) + 4*hi ----
#pragma unroll
        for (int kt = 0; kt < 4; ++kt) {
            union { __hip_bfloat16 hh[8]; bf16x8 v; } pa;
            const int rb = (kt & 1) * 8;
#pragma unroll
            for (int j = 0; j < 8; ++j)
                pa.hh[j] = __float2bfloat16(kt < 2 ? s0[rb + j] : s1[rb + j]);
#pragma unroll
            for (int nt = 0; nt < 2; ++nt) {
                const int row = nt * 32 + l32;
                union { unsigned long long d[2]; bf16x8 v; } vb;
                vb.d[0] = *reinterpret_cast<const unsigned long long*>(
                    Vc + row * 128 + ((kt * 32 + 8 * hi) ^ swz));
                vb.d[1] = *reinterpret_cast<const unsigned long long*>(
                    Vc + row * 128 + ((kt * 32 + 16 + 8 * hi) ^ swz));
                acco[nt] = __builtin_amdgcn_mfma_f32_32x32x16_bf16(pa.v, vb.v, acco[nt], 0, 0, 0);
            }
        }
        asm volatile("s_waitcnt vmcnt(0)" ::: "memory");
        __syncthreads();
        cur ^= 1;
    }

    // ---- epilogue: C row = q-offset = (r&3)+8*(r>>2)+4*hi, col = dh = nt*32+l32 ----
#pragma unroll
    for (int nt = 0; nt < 2; ++nt) {
#pragma unroll
        for (int r = 0; r < 16; ++r) {
            int q = qbase + (r & 3) + 8 * (r >> 2) + 4 * hi;
            ao[(size_t)(b_ * SEQ + q) * DMODEL + h * 64 + nt * 32 + l32] =
                __float2bfloat16(acco[nt][r]);
        }
    }
}

// ---------------- output projection GEMM + bias (f32 out) ----------------
__launch_bounds__(256)
__global__ void outproj_kernel(const __hip_bfloat16* __restrict__ ao,
                               const __hip_bfloat16* __restrict__ WoT,
                               const float* __restrict__ bout,
                               float* __restrict__ out) {
    const int lane = threadIdx.x & 63;
    const int wave = threadIdx.x >> 6;
    const int lr = lane & 15;
    const int lk = lane >> 4;
    const int mbase = blockIdx.y * 64 + wave * 16;
    const int nbase = blockIdx.x * 64;

    const __hip_bfloat16* arow = &ao[(size_t)(mbase + lr) * DMODEL + lk * 8];
    const __hip_bfloat16* brow = &WoT[(size_t)(nbase + lr) * DMODEL + lk * 8];

    bf16x8 a  = *reinterpret_cast<const bf16x8*>(arow);
    bf16x8 b0 = *reinterpret_cast<const bf16x8*>(brow);
    bf16x8 b1 = *reinterpret_cast<const bf16x8*>(brow + 16 * DMODEL);
    bf16x8 b2 = *reinterpret_cast<const bf16x8*>(brow + 32 * DMODEL);
    bf16x8 b3 = *reinterpret_cast<const bf16x8*>(brow + 48 * DMODEL);
    f32x4 acc[4] = {};
    for (int k0 = 0; k0 < DMODEL; k0 += 32) {
        const int kn = (k0 + 32) & (DMODEL - 1);
        bf16x8 an  = *reinterpret_cast<const bf16x8*>(arow + kn);
        bf16x8 bn0 = *reinterpret_cast<const bf16x8*>(brow + kn);
        bf16x8 bn1 = *reinterpret_cast<const bf16x8*>(brow + 16 * DMODEL + kn);
        bf16x8 bn2 = *reinterpret_cast<const bf16x8*>(brow + 32 * DMODEL + kn);
        bf16x8 bn3 = *reinterpret_cast<const bf16x8*>(brow + 48 * DMODEL + kn);
        acc[0] = __builtin_amdgcn_mfma_f32_16x16x32_bf16(a, b0, acc[0], 0, 0, 0);
        acc[1] = __builtin_amdgcn_mfma_f32_16x16x32_bf16(a, b1, acc[1], 0, 0, 0);
        acc[2] = __builtin_amdgcn_mfma_f32_16x16x32_bf16(a, b2, acc[2], 0, 0, 0);
        acc[3] = __builtin_amdgcn_mfma_f32_16x16x32_bf16(a, b3, acc[3], 0, 0, 0);
        a = an; b0 = bn0; b1 = bn1; b2 = bn2; b3 = bn3;
    }
#pragma unroll
    for (int nt = 0; nt < 4; ++nt) {
        float bias = bout[nbase + nt * 16 + lr];
#pragma unroll
        for (int r = 0; r < 4; ++r) {
            int m = mbase + lk * 4 + r;
            out[(size_t)m * DMODEL + nbase + nt * 16 + lr] = acc[nt][r] + bias;
        }
    }
}

extern "C" void kernel_launch(void* const* d_in, const int* in_sizes, int n_in,
                              void* d_out, int out_size, void* d_ws, size_t ws_size,
                              hipStream_t stream) {
    const float* hs   = (const float*)d_in[0];
    const float* Wq   = (const float*)d_in[1];
    const float* Wkv  = (const float*)d_in[2];
    const float* Wout = (const float*)d_in[3];
    const float* bout = (const float*)d_in[4];
    float* out = (float*)d_out;

    char* ws = (char*)d_ws;
    size_t off = 0;
    auto alloc = [&](size_t bytes) { char* p = ws + off; off += bytes; return p; };
    __hip_bfloat16* hsb  = (__hip_bfloat16*)alloc((size_t)MROWS * DMODEL * 2); // dead after proj
    __hip_bfloat16* WqT  = (__hip_bfloat16*)alloc((size_t)DMODEL * DMODEL * 2);
    __hip_bfloat16* WkvT = (__hip_bfloat16*)alloc((size_t)DMODEL * DMODEL * 2);
    __hip_bfloat16* WoT  = (__hip_bfloat16*)alloc((size_t)DMODEL * DMODEL * 2);
    __hip_bfloat16* qb   = (__hip_bfloat16*)alloc((size_t)MROWS * DMODEL * 2);
    __hip_bfloat16* kb   = (__hip_bfloat16*)alloc((size_t)MROWS * DMODEL * 2);
    __hip_bfloat16* vtb  = (__hip_bfloat16*)alloc((size_t)MROWS * DMODEL * 2);
    __hip_bfloat16* ao   = hsb;  // alias: hs_bf16 is dead once attention runs

    // 1. casts / transposes
    cvt_kernel<<<(MROWS * DMODEL / 4 + 255) / 256, 256, 0, stream>>>(hs, hsb, MROWS * DMODEL / 4);
    dim3 trg(32, 32), trb(32, 32);
    tr_kernel<<<trg, trb, 0, stream>>>(Wq, WqT);
    tr_kernel<<<trg, trb, 0, stream>>>(Wkv, WkvT);
    tr_kernel<<<trg, trb, 0, stream>>>(Wout, WoT);

    // 2. fused Q/KV projection (Q pre-scaled by 1/8)
    proj_kernel<<<dim3(2 * DMODEL / 64, MROWS / 64), 256, 0, stream>>>(hsb, WqT, WkvT, qb, kb, vtb);

    // 3. fused relu attention
    attn_kernel<<<NBATCH * HEADS * (SEQ / 128), 256, 0, stream>>>(qb, kb, vtb, ao);

    // 4. output projection
    outproj_kernel<<<dim3(DMODEL / 64, MROWS / 64), 256, 0, stream>>>(ao, WoT, bout, out);
}

// Round 4
// 142.356 us; speedup vs baseline: 3.3879x; 2.1098x over previous
//
#include <hip/hip_runtime.h>
#include <hip/hip_bf16.h>

#define HEADS  16
#define DIMH   64
#define NBATCH 2
#define SEQ    2048
#define DMODEL 1024
#define MROWS  (NBATCH * SEQ)   // 4096

typedef __attribute__((ext_vector_type(8)))  short bf16x8;
typedef __attribute__((ext_vector_type(4)))  float f32x4;
typedef __attribute__((ext_vector_type(16))) float f32x16;
typedef __attribute__((ext_vector_type(4)))  float float4v;
typedef __attribute__((ext_vector_type(4)))  short short4v;

__device__ inline void glds16(const void* g, void* l) {
    __builtin_amdgcn_global_load_lds(
        (const __attribute__((address_space(1))) unsigned int*)g,
        (__attribute__((address_space(3))) unsigned int*)l, 16, 0, 0);
}

// ---------------- f32 -> bf16 cast (4 elems/thread) ----------------
__global__ void cvt_kernel(const float* __restrict__ in,
                           __hip_bfloat16* __restrict__ out, int n4) {
    int i = blockIdx.x * blockDim.x + threadIdx.x;
    if (i >= n4) return;
    float4v v = reinterpret_cast<const float4v*>(in)[i];
    union { short4v s; __hip_bfloat16 h[4]; } u;
#pragma unroll
    for (int j = 0; j < 4; ++j) u.h[j] = __float2bfloat16(v[j]);
    reinterpret_cast<short4v*>(out)[i] = u.s;
}

// ------------- W [D][D] f32 -> WT [o][i] bf16 (transpose+cast) -------------
__global__ void tr_kernel(const float* __restrict__ W,
                          __hip_bfloat16* __restrict__ WT) {
    __shared__ float tile[32][33];
    int i = blockIdx.y * 32 + threadIdx.y;   // row of W
    int o = blockIdx.x * 32 + threadIdx.x;   // col of W
    tile[threadIdx.y][threadIdx.x] = W[i * DMODEL + o];
    __syncthreads();
    int oo = blockIdx.x * 32 + threadIdx.y;  // row of WT
    int ii = blockIdx.y * 32 + threadIdx.x;  // col of WT
    WT[oo * DMODEL + ii] = __float2bfloat16(tile[threadIdx.x][threadIdx.y]);
}

// ============ m97-structure GEMM core (128x128 tile, BK=32) ============
// A [M][1024] bf16 row-major; B [N][1024] bf16 row-major (i.e. C = A @ B^T).
// LDS staged in FRAGMENT ORDER: frag-block f (rows f*16..f*16+15, full 32-k)
// lives at lds[f*1024 + lane*16] where lane = (row&15) + 16*(kchunk).
// global_load_lds writes dest+lane*16 linearly; we permute the per-lane
// GLOBAL source to match -> every ds_read_b128 is base+lane*16, conflict-free.

// ---------------- fused Q/KV projection GEMM ----------------
__launch_bounds__(256, 2)
__global__ void proj_kernel(const __hip_bfloat16* __restrict__ hsb,
                            const __hip_bfloat16* __restrict__ WqT,
                            const __hip_bfloat16* __restrict__ WkvT,
                            __hip_bfloat16* __restrict__ qb,
                            __hip_bfloat16* __restrict__ kb,
                            __hip_bfloat16* __restrict__ vtb) {
    __shared__ __align__(16) char Alds[2][8192];
    __shared__ __align__(16) char Blds[2][8192];
    const int lane = threadIdx.x & 63;
    const int wave = threadIdx.x >> 6;
    const int lr = lane & 15;
    const int lk = lane >> 4;
    const int wm = wave >> 1, wn = wave & 1;

    // bijective XCD swizzle: 512 blocks, 64 contiguous ids per XCD
    int bid = blockIdx.x;
    bid = (bid & 7) * 64 + (bid >> 3);
    const int xt = bid & 15;              // n-tile 0..15 (q: 0..7, kv: 8..15)
    const int mt = bid >> 4;              // m-tile 0..31
    const bool is_q = xt < 8;
    const int mbase = mt * 128;
    const int nbase = (xt & 7) * 128;     // within selected weight matrix
    const __hip_bfloat16* __restrict__ WT = is_q ? WqT : WkvT;

    const char* __restrict__ Ab = (const char*)(hsb + (size_t)mbase * DMODEL);
    const char* __restrict__ Bb = (const char*)(WT + (size_t)nbase * DMODEL);

    auto stage = [&](int buf, int k0) {
#pragma unroll
        for (int p = 0; p < 2; ++p) {
            const int f = wave * 2 + p;   // frag-block 0..7
            const size_t srcoff = (size_t)(f * 16 + lr) * (DMODEL * 2) + k0 * 2 + lk * 16;
            glds16(Ab + srcoff, &Alds[buf][f * 1024]);
            glds16(Bb + srcoff, &Blds[buf][f * 1024]);
        }
    };

    stage(0, 0);
    asm volatile("s_waitcnt vmcnt(0)" ::: "memory");
    __syncthreads();

    f32x4 acc[4][4] = {};
    int cur = 0;
    for (int k0 = 0; k0 < DMODEL; k0 += 32) {
        if (k0 + 32 < DMODEL) stage(cur ^ 1, k0 + 32);
        bf16x8 af[4], bfr[4];
#pragma unroll
        for (int i = 0; i < 4; ++i) {
            af[i]  = *reinterpret_cast<const bf16x8*>(&Alds[cur][(wm * 4 + i) * 1024 + lane * 16]);
            bfr[i] = *reinterpret_cast<const bf16x8*>(&Blds[cur][(wn * 4 + i) * 1024 + lane * 16]);
        }
#pragma unroll
        for (int i = 0; i < 4; ++i)
#pragma unroll
            for (int j = 0; j < 4; ++j)
                acc[i][j] = __builtin_amdgcn_mfma_f32_16x16x32_bf16(af[i], bfr[j], acc[i][j], 0, 0, 0);
        asm volatile("s_waitcnt vmcnt(0)" ::: "memory");
        __syncthreads();
        cur ^= 1;
    }

    // epilogue: C row m = mbase+wm*64+i*16+lk*4+r, col n = nbase'+wn*64+j*16+lr
    const float qscale = is_q ? 0.125f : 1.0f;   // fold attention scale into Q
#pragma unroll
    for (int i = 0; i < 4; ++i) {
#pragma unroll
        for (int j = 0; j < 4; ++j) {
#pragma unroll
            for (int r = 0; r < 4; ++r) {
                int m = mbase + wm * 64 + i * 16 + lk * 4 + r;
                int b_ = m >> 11, s = m & (SEQ - 1);
                int n = nbase + wn * 64 + j * 16 + lr;   // 0..1023 in-matrix
                int h = n >> 6, dh = n & 63;
                __hip_bfloat16 hv = __float2bfloat16(acc[i][j][r] * qscale);
                size_t idx = ((size_t)(b_ * HEADS + h) * SEQ + s) * DIMH + dh;
                if (is_q) {
                    qb[idx] = hv;
                } else {
                    kb[idx] = hv;
                    vtb[((size_t)(b_ * HEADS + h) * DIMH + dh) * SEQ + s] = hv;
                }
            }
        }
    }
}

// ---------------- output projection GEMM + bias (f32 out) ----------------
__launch_bounds__(256, 2)
__global__ void outproj_kernel(const __hip_bfloat16* __restrict__ ao,
                               const __hip_bfloat16* __restrict__ WoT,
                               const float* __restrict__ bout,
                               float* __restrict__ out) {
    __shared__ __align__(16) char Alds[2][8192];
    __shared__ __align__(16) char Blds[2][8192];
    const int lane = threadIdx.x & 63;
    const int wave = threadIdx.x >> 6;
    const int lr = lane & 15;
    const int lk = lane >> 4;
    const int wm = wave >> 1, wn = wave & 1;

    // bijective XCD swizzle: 256 blocks, 32 contiguous ids per XCD
    int bid = blockIdx.x;
    bid = (bid & 7) * 32 + (bid >> 3);
    const int xt = bid & 7;               // n-tile 0..7
    const int mt = bid >> 3;              // m-tile 0..31
    const int mbase = mt * 128;
    const int nbase = xt * 128;

    const char* __restrict__ Ab = (const char*)(ao + (size_t)mbase * DMODEL);
    const char* __restrict__ Bb = (const char*)(WoT + (size_t)nbase * DMODEL);

    auto stage = [&](int buf, int k0) {
#pragma unroll
        for (int p = 0; p < 2; ++p) {
            const int f = wave * 2 + p;
            const size_t srcoff = (size_t)(f * 16 + lr) * (DMODEL * 2) + k0 * 2 + lk * 16;
            glds16(Ab + srcoff, &Alds[buf][f * 1024]);
            glds16(Bb + srcoff, &Blds[buf][f * 1024]);
        }
    };

    stage(0, 0);
    asm volatile("s_waitcnt vmcnt(0)" ::: "memory");
    __syncthreads();

    f32x4 acc[4][4] = {};
    int cur = 0;
    for (int k0 = 0; k0 < DMODEL; k0 += 32) {
        if (k0 + 32 < DMODEL) stage(cur ^ 1, k0 + 32);
        bf16x8 af[4], bfr[4];
#pragma unroll
        for (int i = 0; i < 4; ++i) {
            af[i]  = *reinterpret_cast<const bf16x8*>(&Alds[cur][(wm * 4 + i) * 1024 + lane * 16]);
            bfr[i] = *reinterpret_cast<const bf16x8*>(&Blds[cur][(wn * 4 + i) * 1024 + lane * 16]);
        }
#pragma unroll
        for (int i = 0; i < 4; ++i)
#pragma unroll
            for (int j = 0; j < 4; ++j)
                acc[i][j] = __builtin_amdgcn_mfma_f32_16x16x32_bf16(af[i], bfr[j], acc[i][j], 0, 0, 0);
        asm volatile("s_waitcnt vmcnt(0)" ::: "memory");
        __syncthreads();
        cur ^= 1;
    }

#pragma unroll
    for (int j = 0; j < 4; ++j) {
        const int n = nbase + wn * 64 + j * 16 + lr;
        const float bias = bout[n];
#pragma unroll
        for (int i = 0; i < 4; ++i) {
#pragma unroll
            for (int r = 0; r < 4; ++r) {
                int m = mbase + wm * 64 + i * 16 + lk * 4 + r;
                out[(size_t)m * DMODEL + n] = acc[i][j][r] + bias;
            }
        }
    }
}

// ---------------- fused ReLU attention, 32x32 MFMA + LDS-staged K/V ----------------
__launch_bounds__(256, 2)
__global__ void attn_kernel(const __hip_bfloat16* __restrict__ qb,
                            const __hip_bfloat16* __restrict__ kb,
                            const __hip_bfloat16* __restrict__ vtb,
                            __hip_bfloat16* __restrict__ ao) {
    __shared__ __align__(16) char Klds[2][8192];
    __shared__ __align__(16) char Vlds[2][8192];
    const int lane = threadIdx.x & 63;
    const int wave = threadIdx.x >> 6;
    const int l32  = lane & 31;
    const int hi   = lane >> 5;

    int bid = blockIdx.x;
    bid = (bid & 7) * 64 + (bid >> 3);
    const int bh   = bid >> 4;            // 0..31  (= b*16 + h)
    const int qblk = bid & 15;            // 0..15
    const int b_ = bh >> 4, h = bh & 15;
    const int qbase = qblk * 128 + wave * 32;

    const __hip_bfloat16* __restrict__ Q = qb + (size_t)bh * SEQ * DIMH;
    const char* __restrict__ Kg = (const char*)(kb  + (size_t)bh * SEQ * DIMH);
    const char* __restrict__ Vg = (const char*)(vtb + (size_t)bh * DIMH * SEQ);

    bf16x8 qf[4];
#pragma unroll
    for (int ks = 0; ks < 4; ++ks)
        qf[ks] = *reinterpret_cast<const bf16x8*>(
            &Q[(size_t)(qbase + l32) * DIMH + ks * 16 + hi * 8]);

    f32x16 acco[2] = {};

    auto stage = [&](int buf, int t0) {
#pragma unroll
        for (int pass = 0; pass < 2; ++pass) {
            const int b   = wave * 2048 + pass * 1024 + lane * 16;
            const int row = b >> 7;
            const int cb  = (b & 127) ^ ((row & 7) << 4);
            glds16(Kg + (size_t)(t0 + row) * 128 + cb,
                   &Klds[buf][wave * 2048 + pass * 1024]);
            glds16(Vg + (size_t)row * (SEQ * 2) + t0 * 2 + cb,
                   &Vlds[buf][wave * 2048 + pass * 1024]);
        }
    };

    stage(0, 0);
    asm volatile("s_waitcnt vmcnt(0)" ::: "memory");
    __syncthreads();

    const int swz = (l32 & 7) << 4;
    int cur = 0;
    for (int t0 = 0; t0 < SEQ; t0 += 64) {
        if (t0 + 64 < SEQ) stage(cur ^ 1, t0 + 64);
        const char* Kc = Klds[cur];
        const char* Vc = Vlds[cur];

        f32x16 s0 = {}, s1 = {};
#pragma unroll
        for (int ks = 0; ks < 4; ++ks) {
            bf16x8 k0f = *reinterpret_cast<const bf16x8*>(
                Kc + l32 * 128        + ((ks * 32 + 16 * hi) ^ swz));
            bf16x8 k1f = *reinterpret_cast<const bf16x8*>(
                Kc + (32 + l32) * 128 + ((ks * 32 + 16 * hi) ^ swz));
            s0 = __builtin_amdgcn_mfma_f32_32x32x16_bf16(k0f, qf[ks], s0, 0, 0, 0);
            s1 = __builtin_amdgcn_mfma_f32_32x32x16_bf16(k1f, qf[ks], s1, 0, 0, 0);
        }
#pragma unroll
        for (int r = 0; r < 16; ++r) {
            s0[r] = fmaxf(s0[r], 0.f);
            s1[r] = fmaxf(s1[r], 0.f);
        }
#pragma unroll
        for (int kt = 0; kt < 4; ++kt) {
            union { __hip_bfloat16 hh[8]; bf16x8 v; } pa;
            const int rb = (kt & 1) * 8;
#pragma unroll
            for (int j = 0; j < 8; ++j)
                pa.hh[j] = __float2bfloat16(kt < 2 ? s0[rb + j] : s1[rb + j]);
#pragma unroll
            for (int nt = 0; nt < 2; ++nt) {
                const int row = nt * 32 + l32;
                union { unsigned long long d[2]; bf16x8 v; } vb;
                vb.d[0] = *reinterpret_cast<const unsigned long long*>(
                    Vc + row * 128 + ((kt * 32 + 8 * hi) ^ swz));
                vb.d[1] = *reinterpret_cast<const unsigned long long*>(
                    Vc + row * 128 + ((kt * 32 + 16 + 8 * hi) ^ swz));
                acco[nt] = __builtin_amdgcn_mfma_f32_32x32x16_bf16(pa.v, vb.v, acco[nt], 0, 0, 0);
            }
        }
        asm volatile("s_waitcnt vmcnt(0)" ::: "memory");
        __syncthreads();
        cur ^= 1;
    }

#pragma unroll
    for (int nt = 0; nt < 2; ++nt) {
#pragma unroll
        for (int r = 0; r < 16; ++r) {
            int q = qbase + (r & 3) + 8 * (r >> 2) + 4 * hi;
            ao[(size_t)(b_ * SEQ + q) * DMODEL + h * 64 + nt * 32 + l32] =
                __float2bfloat16(acco[nt][r]);
        }
    }
}

extern "C" void kernel_launch(void* const* d_in, const int* in_sizes, int n_in,
                              void* d_out, int out_size, void* d_ws, size_t ws_size,
                              hipStream_t stream) {
    const float* hs   = (const float*)d_in[0];
    const float* Wq   = (const float*)d_in[1];
    const float* Wkv  = (const float*)d_in[2];
    const float* Wout = (const float*)d_in[3];
    const float* bout = (const float*)d_in[4];
    float* out = (float*)d_out;

    char* ws = (char*)d_ws;
    size_t off = 0;
    auto alloc = [&](size_t bytes) { char* p = ws + off; off += bytes; return p; };
    __hip_bfloat16* hsb  = (__hip_bfloat16*)alloc((size_t)MROWS * DMODEL * 2); // dead after proj
    __hip_bfloat16* WqT  = (__hip_bfloat16*)alloc((size_t)DMODEL * DMODEL * 2);
    __hip_bfloat16* WkvT = (__hip_bfloat16*)alloc((size_t)DMODEL * DMODEL * 2);
    __hip_bfloat16* WoT  = (__hip_bfloat16*)alloc((size_t)DMODEL * DMODEL * 2);
    __hip_bfloat16* qb   = (__hip_bfloat16*)alloc((size_t)MROWS * DMODEL * 2);
    __hip_bfloat16* kb   = (__hip_bfloat16*)alloc((size_t)MROWS * DMODEL * 2);
    __hip_bfloat16* vtb  = (__hip_bfloat16*)alloc((size_t)MROWS * DMODEL * 2);
    __hip_bfloat16* ao   = hsb;  // alias: hs_bf16 is dead once attention runs

    // 1. casts / transposes
    cvt_kernel<<<(MROWS * DMODEL / 4 + 255) / 256, 256, 0, stream>>>(hs, hsb, MROWS * DMODEL / 4);
    dim3 trg(32, 32), trb(32, 32);
    tr_kernel<<<trg, trb, 0, stream>>>(Wq, WqT);
    tr_kernel<<<trg, trb, 0, stream>>>(Wkv, WkvT);
    tr_kernel<<<trg, trb, 0, stream>>>(Wout, WoT);

    // 2. fused Q/KV projection (Q pre-scaled by 1/8): 512 blocks
    proj_kernel<<<16 * (MROWS / 128), 256, 0, stream>>>(hsb, WqT, WkvT, qb, kb, vtb);

    // 3. fused relu attention
    attn_kernel<<<NBATCH * HEADS * (SEQ / 128), 256, 0, stream>>>(qb, kb, vtb, ao);

    // 4. output projection: 256 blocks
    outproj_kernel<<<8 * (MROWS / 128), 256, 0, stream>>>(ao, WoT, bout, out);
}

// Round 5
// 141.988 us; speedup vs baseline: 3.3966x; 1.0026x over previous
//
#include <hip/hip_runtime.h>
#include <hip/hip_bf16.h>

#define HEADS  16
#define DIMH   64
#define NBATCH 2
#define SEQ    2048
#define DMODEL 1024
#define MROWS  (NBATCH * SEQ)   // 4096

typedef __attribute__((ext_vector_type(8)))  short bf16x8;
typedef __attribute__((ext_vector_type(4)))  float f32x4;
typedef __attribute__((ext_vector_type(16))) float f32x16;
typedef __attribute__((ext_vector_type(4)))  float float4v;
typedef __attribute__((ext_vector_type(4)))  short short4v;

__device__ inline void glds16(const void* g, void* l) {
    __builtin_amdgcn_global_load_lds(
        (const __attribute__((address_space(1))) unsigned int*)g,
        (__attribute__((address_space(3))) unsigned int*)l, 16, 0, 0);
}

// counted-vmcnt helpers: each stage() = 4 glds16/wave; depth-2 prefetch keeps
// 8 in flight; vmcnt(4) retires exactly the oldest stage's loads (m135).
#define WAIT_VMCNT4() asm volatile("s_waitcnt vmcnt(4)" ::: "memory")
#define WAIT_VMCNT0() asm volatile("s_waitcnt vmcnt(0)" ::: "memory")
#define BARRIER() do { __builtin_amdgcn_s_barrier(); asm volatile("" ::: "memory"); } while (0)

// ---------------- f32 -> bf16 cast (4 elems/thread) ----------------
__global__ void cvt_kernel(const float* __restrict__ in,
                           __hip_bfloat16* __restrict__ out, int n4) {
    int i = blockIdx.x * blockDim.x + threadIdx.x;
    if (i >= n4) return;
    float4v v = reinterpret_cast<const float4v*>(in)[i];
    union { short4v s; __hip_bfloat16 h[4]; } u;
#pragma unroll
    for (int j = 0; j < 4; ++j) u.h[j] = __float2bfloat16(v[j]);
    reinterpret_cast<short4v*>(out)[i] = u.s;
}

// ------------- W [D][D] f32 -> WT [o][i] bf16 (transpose+cast) -------------
__global__ void tr_kernel(const float* __restrict__ W,
                          __hip_bfloat16* __restrict__ WT) {
    __shared__ float tile[32][33];
    int i = blockIdx.y * 32 + threadIdx.y;   // row of W
    int o = blockIdx.x * 32 + threadIdx.x;   // col of W
    tile[threadIdx.y][threadIdx.x] = W[i * DMODEL + o];
    __syncthreads();
    int oo = blockIdx.x * 32 + threadIdx.y;  // row of WT
    int ii = blockIdx.y * 32 + threadIdx.x;  // col of WT
    WT[oo * DMODEL + ii] = __float2bfloat16(tile[threadIdx.x][threadIdx.y]);
}

// ============ m97-structure GEMM core, counted-vmcnt 3-buffer pipeline ======
// A [M][1024] bf16 row-major; B [N][1024] bf16 row-major (C = A @ B^T).
// LDS staged in FRAGMENT ORDER (frag-block f at lds[f*1024 + lane*16]) by
// permuting the per-lane GLOBAL source; all ds_read_b128 are base+lane*16.

// ---------------- fused Q/KV projection GEMM ----------------
__launch_bounds__(256, 2)
__global__ void proj_kernel(const __hip_bfloat16* __restrict__ hsb,
                            const __hip_bfloat16* __restrict__ WqT,
                            const __hip_bfloat16* __restrict__ WkvT,
                            __hip_bfloat16* __restrict__ qb,
                            __hip_bfloat16* __restrict__ kb,
                            __hip_bfloat16* __restrict__ vtb) {
    __shared__ __align__(16) char Alds[3][8192];
    __shared__ __align__(16) char Blds[3][8192];
    const int lane = threadIdx.x & 63;
    const int wave = threadIdx.x >> 6;
    const int lr = lane & 15;
    const int lk = lane >> 4;
    const int wm = wave >> 1, wn = wave & 1;

    // bijective XCD swizzle: 512 blocks, 64 contiguous ids per XCD
    int bid = blockIdx.x;
    bid = (bid & 7) * 64 + (bid >> 3);
    const int xt = bid & 15;              // n-tile 0..15 (q: 0..7, kv: 8..15)
    const int mt = bid >> 4;              // m-tile 0..31
    const bool is_q = xt < 8;
    const int mbase = mt * 128;
    const int nbase = (xt & 7) * 128;
    const __hip_bfloat16* __restrict__ WT = is_q ? WqT : WkvT;

    const char* __restrict__ Ab = (const char*)(hsb + (size_t)mbase * DMODEL);
    const char* __restrict__ Bb = (const char*)(WT + (size_t)nbase * DMODEL);

    auto stage = [&](int buf, int k0) {
#pragma unroll
        for (int p = 0; p < 2; ++p) {
            const int f = wave * 2 + p;   // frag-block 0..7
            const size_t srcoff = (size_t)(f * 16 + lr) * (DMODEL * 2) + k0 * 2 + lk * 16;
            glds16(Ab + srcoff, &Alds[buf][f * 1024]);
            glds16(Bb + srcoff, &Blds[buf][f * 1024]);
        }
    };

    stage(0, 0);
    stage(1, 32);

    f32x4 acc[4][4] = {};
    int c0 = 0;
    for (int t = 0; t < DMODEL / 32; ++t) {
        if (t < DMODEL / 32 - 1) WAIT_VMCNT4(); else WAIT_VMCNT0();
        BARRIER();
        if (t + 2 < DMODEL / 32) {
            int sb = c0 + 2; if (sb >= 3) sb -= 3;
            stage(sb, (t + 2) * 32);
        }
        bf16x8 af[4], bfr[4];
#pragma unroll
        for (int i = 0; i < 4; ++i) {
            af[i]  = *reinterpret_cast<const bf16x8*>(&Alds[c0][(wm * 4 + i) * 1024 + lane * 16]);
            bfr[i] = *reinterpret_cast<const bf16x8*>(&Blds[c0][(wn * 4 + i) * 1024 + lane * 16]);
        }
#pragma unroll
        for (int i = 0; i < 4; ++i)
#pragma unroll
            for (int j = 0; j < 4; ++j)
                acc[i][j] = __builtin_amdgcn_mfma_f32_16x16x32_bf16(af[i], bfr[j], acc[i][j], 0, 0, 0);
        c0 = (c0 + 1 == 3) ? 0 : c0 + 1;
    }

    const float qscale = is_q ? 0.125f : 1.0f;   // fold attention scale into Q
#pragma unroll
    for (int i = 0; i < 4; ++i) {
#pragma unroll
        for (int j = 0; j < 4; ++j) {
#pragma unroll
            for (int r = 0; r < 4; ++r) {
                int m = mbase + wm * 64 + i * 16 + lk * 4 + r;
                int b_ = m >> 11, s = m & (SEQ - 1);
                int n = nbase + wn * 64 + j * 16 + lr;
                int h = n >> 6, dh = n & 63;
                __hip_bfloat16 hv = __float2bfloat16(acc[i][j][r] * qscale);
                size_t idx = ((size_t)(b_ * HEADS + h) * SEQ + s) * DIMH + dh;
                if (is_q) {
                    qb[idx] = hv;
                } else {
                    kb[idx] = hv;
                    vtb[((size_t)(b_ * HEADS + h) * DIMH + dh) * SEQ + s] = hv;
                }
            }
        }
    }
}

// ---------------- output projection GEMM + bias (f32 out) ----------------
__launch_bounds__(256, 2)
__global__ void outproj_kernel(const __hip_bfloat16* __restrict__ ao,
                               const __hip_bfloat16* __restrict__ WoT,
                               const float* __restrict__ bout,
                               float* __restrict__ out) {
    __shared__ __align__(16) char Alds[3][8192];
    __shared__ __align__(16) char Blds[3][8192];
    const int lane = threadIdx.x & 63;
    const int wave = threadIdx.x >> 6;
    const int lr = lane & 15;
    const int lk = lane >> 4;
    const int wm = wave >> 1, wn = wave & 1;

    // bijective XCD swizzle: 256 blocks, 32 contiguous ids per XCD
    int bid = blockIdx.x;
    bid = (bid & 7) * 32 + (bid >> 3);
    const int xt = bid & 7;
    const int mt = bid >> 3;
    const int mbase = mt * 128;
    const int nbase = xt * 128;

    const char* __restrict__ Ab = (const char*)(ao + (size_t)mbase * DMODEL);
    const char* __restrict__ Bb = (const char*)(WoT + (size_t)nbase * DMODEL);

    auto stage = [&](int buf, int k0) {
#pragma unroll
        for (int p = 0; p < 2; ++p) {
            const int f = wave * 2 + p;
            const size_t srcoff = (size_t)(f * 16 + lr) * (DMODEL * 2) + k0 * 2 + lk * 16;
            glds16(Ab + srcoff, &Alds[buf][f * 1024]);
            glds16(Bb + srcoff, &Blds[buf][f * 1024]);
        }
    };

    stage(0, 0);
    stage(1, 32);

    f32x4 acc[4][4] = {};
    int c0 = 0;
    for (int t = 0; t < DMODEL / 32; ++t) {
        if (t < DMODEL / 32 - 1) WAIT_VMCNT4(); else WAIT_VMCNT0();
        BARRIER();
        if (t + 2 < DMODEL / 32) {
            int sb = c0 + 2; if (sb >= 3) sb -= 3;
            stage(sb, (t + 2) * 32);
        }
        bf16x8 af[4], bfr[4];
#pragma unroll
        for (int i = 0; i < 4; ++i) {
            af[i]  = *reinterpret_cast<const bf16x8*>(&Alds[c0][(wm * 4 + i) * 1024 + lane * 16]);
            bfr[i] = *reinterpret_cast<const bf16x8*>(&Blds[c0][(wn * 4 + i) * 1024 + lane * 16]);
        }
#pragma unroll
        for (int i = 0; i < 4; ++i)
#pragma unroll
            for (int j = 0; j < 4; ++j)
                acc[i][j] = __builtin_amdgcn_mfma_f32_16x16x32_bf16(af[i], bfr[j], acc[i][j], 0, 0, 0);
        c0 = (c0 + 1 == 3) ? 0 : c0 + 1;
    }

#pragma unroll
    for (int j = 0; j < 4; ++j) {
        const int n = nbase + wn * 64 + j * 16 + lr;
        const float bias = bout[n];
#pragma unroll
        for (int i = 0; i < 4; ++i) {
#pragma unroll
            for (int r = 0; r < 4; ++r) {
                int m = mbase + wm * 64 + i * 16 + lk * 4 + r;
                out[(size_t)m * DMODEL + n] = acc[i][j][r] + bias;
            }
        }
    }
}

// ---------------- fused ReLU attention, 32x32 MFMA + LDS-staged K/V ----------------
__launch_bounds__(256, 2)
__global__ void attn_kernel(const __hip_bfloat16* __restrict__ qb,
                            const __hip_bfloat16* __restrict__ kb,
                            const __hip_bfloat16* __restrict__ vtb,
                            __hip_bfloat16* __restrict__ ao) {
    __shared__ __align__(16) char Klds[3][8192];
    __shared__ __align__(16) char Vlds[3][8192];
    const int lane = threadIdx.x & 63;
    const int wave = threadIdx.x >> 6;
    const int l32  = lane & 31;
    const int hi   = lane >> 5;

    int bid = blockIdx.x;
    bid = (bid & 7) * 64 + (bid >> 3);
    const int bh   = bid >> 4;            // 0..31  (= b*16 + h)
    const int qblk = bid & 15;            // 0..15
    const int b_ = bh >> 4, h = bh & 15;
    const int qbase = qblk * 128 + wave * 32;

    const __hip_bfloat16* __restrict__ Q = qb + (size_t)bh * SEQ * DIMH;
    const char* __restrict__ Kg = (const char*)(kb  + (size_t)bh * SEQ * DIMH);
    const char* __restrict__ Vg = (const char*)(vtb + (size_t)bh * DIMH * SEQ);

    bf16x8 qf[4];
#pragma unroll
    for (int ks = 0; ks < 4; ++ks)
        qf[ks] = *reinterpret_cast<const bf16x8*>(
            &Q[(size_t)(qbase + l32) * DIMH + ks * 16 + hi * 8]);

    f32x16 acco[2] = {};

    auto stage = [&](int buf, int t0) {
#pragma unroll
        for (int pass = 0; pass < 2; ++pass) {
            const int b   = wave * 2048 + pass * 1024 + lane * 16;
            const int row = b >> 7;
            const int cb  = (b & 127) ^ ((row & 7) << 4);
            glds16(Kg + (size_t)(t0 + row) * 128 + cb,
                   &Klds[buf][wave * 2048 + pass * 1024]);
            glds16(Vg + (size_t)row * (SEQ * 2) + t0 * 2 + cb,
                   &Vlds[buf][wave * 2048 + pass * 1024]);
        }
    };

    stage(0, 0);
    stage(1, 64);

    const int swz = (l32 & 7) << 4;
    int c0 = 0;
    for (int t0 = 0; t0 < SEQ; t0 += 64) {
        if (t0 + 64 < SEQ) WAIT_VMCNT4(); else WAIT_VMCNT0();
        BARRIER();
        if (t0 + 128 < SEQ) {
            int sb = c0 + 2; if (sb >= 3) sb -= 3;
            stage(sb, t0 + 128);
        }
        const char* Kc = Klds[c0];
        const char* Vc = Vlds[c0];

        // ---- S^T = K Q^T ----
        f32x16 s0 = {}, s1 = {};
#pragma unroll
        for (int ks = 0; ks < 4; ++ks) {
            bf16x8 k0f = *reinterpret_cast<const bf16x8*>(
                Kc + l32 * 128        + ((ks * 32 + 16 * hi) ^ swz));
            bf16x8 k1f = *reinterpret_cast<const bf16x8*>(
                Kc + (32 + l32) * 128 + ((ks * 32 + 16 * hi) ^ swz));
            s0 = __builtin_amdgcn_mfma_f32_32x32x16_bf16(k0f, qf[ks], s0, 0, 0, 0);
            s1 = __builtin_amdgcn_mfma_f32_32x32x16_bf16(k1f, qf[ks], s1, 0, 0, 0);
        }
#pragma unroll
        for (int r = 0; r < 16; ++r) {
            s0[r] = fmaxf(s0[r], 0.f);
            s1[r] = fmaxf(s1[r], 0.f);
        }
        // ---- O += P V (lane-local P; scrambled-t V reads) ----
#pragma unroll
        for (int kt = 0; kt < 4; ++kt) {
            union { __hip_bfloat16 hh[8]; bf16x8 v; } pa;
            const int rb = (kt & 1) * 8;
#pragma unroll
            for (int j = 0; j < 8; ++j)
                pa.hh[j] = __float2bfloat16(kt < 2 ? s0[rb + j] : s1[rb + j]);
#pragma unroll
            for (int nt = 0; nt < 2; ++nt) {
                const int row = nt * 32 + l32;
                union { unsigned long long d[2]; bf16x8 v; } vb;
                vb.d[0] = *reinterpret_cast<const unsigned long long*>(
                    Vc + row * 128 + ((kt * 32 + 8 * hi) ^ swz));
                vb.d[1] = *reinterpret_cast<const unsigned long long*>(
                    Vc + row * 128 + ((kt * 32 + 16 + 8 * hi) ^ swz));
                acco[nt] = __builtin_amdgcn_mfma_f32_32x32x16_bf16(pa.v, vb.v, acco[nt], 0, 0, 0);
            }
        }
        c0 = (c0 + 1 == 3) ? 0 : c0 + 1;
    }

#pragma unroll
    for (int nt = 0; nt < 2; ++nt) {
#pragma unroll
        for (int r = 0; r < 16; ++r) {
            int q = qbase + (r & 3) + 8 * (r >> 2) + 4 * hi;
            ao[(size_t)(b_ * SEQ + q) * DMODEL + h * 64 + nt * 32 + l32] =
                __float2bfloat16(acco[nt][r]);
        }
    }
}

extern "C" void kernel_launch(void* const* d_in, const int* in_sizes, int n_in,
                              void* d_out, int out_size, void* d_ws, size_t ws_size,
                              hipStream_t stream) {
    const float* hs   = (const float*)d_in[0];
    const float* Wq   = (const float*)d_in[1];
    const float* Wkv  = (const float*)d_in[2];
    const float* Wout = (const float*)d_in[3];
    const float* bout = (const float*)d_in[4];
    float* out = (float*)d_out;

    char* ws = (char*)d_ws;
    size_t off = 0;
    auto alloc = [&](size_t bytes) { char* p = ws + off; off += bytes; return p; };
    __hip_bfloat16* hsb  = (__hip_bfloat16*)alloc((size_t)MROWS * DMODEL * 2); // dead after proj
    __hip_bfloat16* WqT  = (__hip_bfloat16*)alloc((size_t)DMODEL * DMODEL * 2);
    __hip_bfloat16* WkvT = (__hip_bfloat16*)alloc((size_t)DMODEL * DMODEL * 2);
    __hip_bfloat16* WoT  = (__hip_bfloat16*)alloc((size_t)DMODEL * DMODEL * 2);
    __hip_bfloat16* qb   = (__hip_bfloat16*)alloc((size_t)MROWS * DMODEL * 2);
    __hip_bfloat16* kb   = (__hip_bfloat16*)alloc((size_t)MROWS * DMODEL * 2);
    __hip_bfloat16* vtb  = (__hip_bfloat16*)alloc((size_t)MROWS * DMODEL * 2);
    __hip_bfloat16* ao   = hsb;  // alias: hs_bf16 is dead once attention runs

    // 1. casts / transposes
    cvt_kernel<<<(MROWS * DMODEL / 4 + 255) / 256, 256, 0, stream>>>(hs, hsb, MROWS * DMODEL / 4);
    dim3 trg(32, 32), trb(32, 32);
    tr_kernel<<<trg, trb, 0, stream>>>(Wq, WqT);
    tr_kernel<<<trg, trb, 0, stream>>>(Wkv, WkvT);
    tr_kernel<<<trg, trb, 0, stream>>>(Wout, WoT);

    // 2. fused Q/KV projection (Q pre-scaled by 1/8): 512 blocks
    proj_kernel<<<16 * (MROWS / 128), 256, 0, stream>>>(hsb, WqT, WkvT, qb, kb, vtb);

    // 3. fused relu attention
    attn_kernel<<<NBATCH * HEADS * (SEQ / 128), 256, 0, stream>>>(qb, kb, vtb, ao);

    // 4. output projection: 256 blocks
    outproj_kernel<<<8 * (MROWS / 128), 256, 0, stream>>>(ao, WoT, bout, out);
}